// Round 1
// baseline (146.393 us; speedup 1.0000x reference)
//
#include <hip/hip_runtime.h>
#include <math.h>

#define N_RAYS    32768
#define N_SAMPLES (N_RAYS * 32)
#define HID  64
#define FDIM 32
#define THRESH 0.0001f

// ---------------------------------------------------------------------------
// Kernel 1: per-sample MLP. One thread per sample.
// Layer1 (3->64) + Layer2 (64->32) fused: h1[j] computed then immediately
// folded into feats[] accumulators. RGB layer (35->64->3) similarly fused.
// Weights are accessed at wave-uniform addresses -> scalar loads.
// Output per sample: float4 {tau, r, g, b} into workspace.
// ---------------------------------------------------------------------------
__global__ __launch_bounds__(256) void nerf_mlp_kernel(
    const float* __restrict__ samples,   // (N_SAMPLES, 7): pos3, dir3, dt
    const float* __restrict__ w1,        // (3, 64)
    const float* __restrict__ b1,        // (64)
    const float* __restrict__ w2,        // (64, 32)
    const float* __restrict__ b2,        // (32)
    const float* __restrict__ w_sigma,   // (32, 1)
    const float* __restrict__ b_sigma,   // (1)
    const float* __restrict__ w_rgb1,    // (35, 64)
    const float* __restrict__ b_rgb1,    // (64)
    const float* __restrict__ w_rgb2,    // (64, 3)
    const float* __restrict__ b_rgb2,    // (3)
    float4* __restrict__ out)            // (N_SAMPLES): tau, r, g, b
{
    const int t = blockIdx.x * blockDim.x + threadIdx.x;
    if (t >= N_SAMPLES) return;

    const float* s = samples + (long)t * 7;
    const float p0 = s[0], p1 = s[1], p2 = s[2];
    const float d0 = s[3], d1 = s[4], d2 = s[5];
    const float dt = s[6];

    // feats = relu(pos @ w1 + b1) @ w2 + b2, fused
    float feats[FDIM];
    #pragma unroll
    for (int k = 0; k < FDIM; ++k) feats[k] = b2[k];

    #pragma unroll 4
    for (int j = 0; j < HID; ++j) {
        float h = fmaf(p2, w1[128 + j], fmaf(p1, w1[64 + j], fmaf(p0, w1[j], b1[j])));
        h = fmaxf(h, 0.0f);
        #pragma unroll
        for (int k = 0; k < FDIM; ++k)
            feats[k] = fmaf(h, w2[j * FDIM + k], feats[k]);
    }

    // sigma = softplus(feats @ w_sigma + b_sigma)
    float sp = b_sigma[0];
    #pragma unroll
    for (int k = 0; k < FDIM; ++k) sp = fmaf(feats[k], w_sigma[k], sp);
    // numerically stable softplus = max(x,0) + log1p(exp(-|x|))
    const float sigma = fmaxf(sp, 0.0f) + log1pf(expf(-fabsf(sp)));
    const float tau = sigma * dt;

    // rgb = sigmoid(relu([feats, dirs] @ w_rgb1 + b_rgb1) @ w_rgb2 + b_rgb2), fused
    float a0 = b_rgb2[0], a1 = b_rgb2[1], a2 = b_rgb2[2];
    #pragma unroll 2
    for (int j = 0; j < HID; ++j) {
        float h = b_rgb1[j];
        #pragma unroll
        for (int k = 0; k < FDIM; ++k)
            h = fmaf(feats[k], w_rgb1[k * HID + j], h);
        h = fmaf(d0, w_rgb1[32 * HID + j], h);
        h = fmaf(d1, w_rgb1[33 * HID + j], h);
        h = fmaf(d2, w_rgb1[34 * HID + j], h);
        h = fmaxf(h, 0.0f);
        a0 = fmaf(h, w_rgb2[j * 3 + 0], a0);
        a1 = fmaf(h, w_rgb2[j * 3 + 1], a1);
        a2 = fmaf(h, w_rgb2[j * 3 + 2], a2);
    }
    const float r = 1.0f / (1.0f + expf(-a0));
    const float g = 1.0f / (1.0f + expf(-a1));
    const float b = 1.0f / (1.0f + expf(-a2));

    out[t] = make_float4(tau, r, g, b);
}

// ---------------------------------------------------------------------------
// Kernel 2: one wave (64 lanes) per ray. counts <= 57 so a single wave covers
// every sample of the ray. Exclusive scan of tau -> T, gate at THRESH, then
// shuffle-reduce weighted rgb + opacity; lane 0 writes the composited color.
// ---------------------------------------------------------------------------
__global__ __launch_bounds__(256) void nerf_render_kernel(
    const float4* __restrict__ smp,      // (N_SAMPLES): tau, r, g, b
    const int*    __restrict__ packing,  // (N_RAYS, 2): start, count
    const float*  __restrict__ bg,       // (3)
    float*        __restrict__ out)      // (N_RAYS, 3)
{
    const int gtid = blockIdx.x * blockDim.x + threadIdx.x;
    const int ray  = gtid >> 6;
    const int lane = threadIdx.x & 63;
    if (ray >= N_RAYS) return;

    const int start = packing[2 * ray];
    const int count = packing[2 * ray + 1];

    float tau = 0.0f, r = 0.0f, g = 0.0f, b = 0.0f;
    if (lane < count) {
        const float4 v = smp[start + lane];
        tau = v.x; r = v.y; g = v.z; b = v.w;
    }

    // inclusive scan of tau across the wave
    float incl = tau;
    #pragma unroll
    for (int off = 1; off < 64; off <<= 1) {
        const float v = __shfl_up(incl, off, 64);
        if (lane >= off) incl += v;
    }
    const float c_excl = incl - tau;

    const float T     = expf(-c_excl);
    const float alpha = 1.0f - expf(-tau);
    float w = (lane < count && T > THRESH) ? T * alpha : 0.0f;

    float cr = r * w, cg = g * w, cb = b * w;

    #pragma unroll
    for (int off = 32; off > 0; off >>= 1) {
        cr += __shfl_down(cr, off, 64);
        cg += __shfl_down(cg, off, 64);
        cb += __shfl_down(cb, off, 64);
        w  += __shfl_down(w,  off, 64);
    }

    if (lane == 0) {
        out[ray * 3 + 0] = cr + bg[0] * (1.0f - w);
        out[ray * 3 + 1] = cg + bg[1] * (1.0f - w);
        out[ray * 3 + 2] = cb + bg[2] * (1.0f - w);
    }
}

extern "C" void kernel_launch(void* const* d_in, const int* in_sizes, int n_in,
                              void* d_out, int out_size, void* d_ws, size_t ws_size,
                              hipStream_t stream) {
    const float* samples  = (const float*)d_in[0];   // (N_SAMPLES, 7)
    const int*   packing  = (const int*)  d_in[1];   // (N_RAYS, 2)
    // d_in[2] = ray_ids (unused; packing_info is sufficient)
    const float* w1       = (const float*)d_in[3];
    const float* b1       = (const float*)d_in[4];
    const float* w2       = (const float*)d_in[5];
    const float* b2       = (const float*)d_in[6];
    const float* w_sigma  = (const float*)d_in[7];
    const float* b_sigma  = (const float*)d_in[8];
    const float* w_rgb1   = (const float*)d_in[9];
    const float* b_rgb1   = (const float*)d_in[10];
    const float* w_rgb2   = (const float*)d_in[11];
    const float* b_rgb2   = (const float*)d_in[12];
    const float* bg       = (const float*)d_in[13];

    float4* smp = (float4*)d_ws;           // N_SAMPLES * 16 B = 16 MiB
    float*  out = (float*)d_out;

    {
        const int threads = 256;
        const int blocks  = (N_SAMPLES + threads - 1) / threads;
        nerf_mlp_kernel<<<blocks, threads, 0, stream>>>(
            samples, w1, b1, w2, b2, w_sigma, b_sigma,
            w_rgb1, b_rgb1, w_rgb2, b_rgb2, smp);
    }
    {
        // one 64-lane wave per ray, 4 rays per 256-thread block
        const int threads = 256;
        const int blocks  = (N_RAYS * 64) / threads;
        nerf_render_kernel<<<blocks, threads, 0, stream>>>(smp, packing, bg, out);
    }
}

// Round 2
// 73.145 us; speedup vs baseline: 2.0014x; 2.0014x over previous
//
#include <hip/hip_runtime.h>
#include <math.h>
#include <stdint.h>

#define N_RAYS    32768
#define N_SAMPLES (N_RAYS * 32)
#define THRESH 0.0001f

typedef __attribute__((ext_vector_type(8))) __bf16 bf16x8;
typedef __attribute__((ext_vector_type(4))) float  f32x4;

union FragU { uint32_t w[4]; bf16x8 v; uint2 d[2]; };

__device__ inline uint32_t cvt_pk_bf16(float lo, float hi) {
    uint32_t r;
    asm("v_cvt_pk_bf16_f32 %0, %1, %2" : "=v"(r) : "v"(lo), "v"(hi));
    return r;
}

__device__ inline bf16x8 pack8(const float* vals) {
    FragU u;
    u.w[0] = cvt_pk_bf16(vals[0], vals[1]);
    u.w[1] = cvt_pk_bf16(vals[2], vals[3]);
    u.w[2] = cvt_pk_bf16(vals[4], vals[5]);
    u.w[3] = cvt_pk_bf16(vals[6], vals[7]);
    return u.v;
}

// ---------------------------------------------------------------------------
// MFMA MLP: one wave = 16 samples (sample index on lane&15 = B/N axis).
// All layers computed as weight^T (A) x activations (B), 16x16x32 bf16 MFMA.
// D layout (verified): n = lane&15, m = 4*(lane>>4) + reg.
// A/B k-slot convention (self-consistent, HW-permutation-proof): slot (g=lane>>4,
// reg r) <-> k = 32*kstep + 8g + r.
// D->B boundaries go through wave-private LDS with 16B-granule XOR swizzle.
// ---------------------------------------------------------------------------
__global__ __launch_bounds__(256, 2) void nerf_mlp_mfma(
    const float* __restrict__ samples,   // (N_SAMPLES, 7)
    const float* __restrict__ w1,        // (3, 64)
    const float* __restrict__ b1,        // (64)
    const float* __restrict__ w2,        // (64, 32)
    const float* __restrict__ b2,        // (32)
    const float* __restrict__ w_sigma,   // (32, 1)
    const float* __restrict__ b_sigma,   // (1)
    const float* __restrict__ w_rgb1,    // (35, 64)
    const float* __restrict__ b_rgb1,    // (64)
    const float* __restrict__ w_rgb2,    // (64, 3)
    const float* __restrict__ b_rgb2,    // (3)
    float4* __restrict__ out)            // (N_SAMPLES): tau, r, g, b
{
    __shared__ __align__(16) char lds_all[4][3072];
    const int wid  = threadIdx.x >> 6;
    const int lane = threadIdx.x & 63;
    const int g    = lane >> 4;
    const int sl   = lane & 15;
    char* hbuf = lds_all[wid];           // 16 rows x 128 B (64 bf16): h1 then h
    char* fbuf = lds_all[wid] + 2048;    // 16 rows x  64 B (32 bf16): feats

    // ---------------- hoisted weight fragments (per wave) ----------------
    bf16x8 A1[4], A2[2][2], Ar1a[4], Ar1b[4], Ar2[2];

    // A1 = w1aug^T (64x4 in K=32): M=j -> 4 tiles; k: 0..2 = w1 rows, 3 = b1
    #pragma unroll
    for (int t = 0; t < 4; ++t) {
        float v[8] = {0,0,0,0,0,0,0,0};
        if (g == 0) {
            const int j = t*16 + sl;
            v[0] = w1[j]; v[1] = w1[64+j]; v[2] = w1[128+j]; v[3] = b1[j];
        }
        A1[t] = pack8(v);
    }
    // A2 = w2^T (32x64): M=f -> 2 tiles; K=64 -> 2 ksteps
    #pragma unroll
    for (int t = 0; t < 2; ++t)
        #pragma unroll
        for (int c = 0; c < 2; ++c) {
            float v[8];
            #pragma unroll
            for (int r = 0; r < 8; ++r)
                v[r] = w2[(32*c + 8*g + r)*32 + t*16 + sl];
            A2[t][c] = pack8(v);
        }
    // Ar1a = w_rgb1^T rows 0..31 (feats part): M=j -> 4 tiles; K=32
    #pragma unroll
    for (int t = 0; t < 4; ++t) {
        float v[8];
        #pragma unroll
        for (int r = 0; r < 8; ++r)
            v[r] = w_rgb1[(8*g + r)*64 + t*16 + sl];
        Ar1a[t] = pack8(v);
    }
    // Ar1b = dirs rows 32..34 + bias aug (k-local 3): M=j -> 4 tiles
    #pragma unroll
    for (int t = 0; t < 4; ++t) {
        float v[8] = {0,0,0,0,0,0,0,0};
        if (g == 0) {
            const int j = t*16 + sl;
            v[0] = w_rgb1[32*64 + j]; v[1] = w_rgb1[33*64 + j];
            v[2] = w_rgb1[34*64 + j]; v[3] = b_rgb1[j];
        }
        Ar1b[t] = pack8(v);
    }
    // Ar2 = w_rgb2^T (3x64): M=channel on sl (sl<3); K=64 -> 2 ksteps
    #pragma unroll
    for (int c = 0; c < 2; ++c) {
        float v[8];
        #pragma unroll
        for (int r = 0; r < 8; ++r)
            v[r] = (sl < 3) ? w_rgb2[(32*c + 8*g + r)*3 + sl] : 0.0f;
        Ar2[c] = pack8(v);
    }
    // per-lane sigma weights and b2 (this lane's feat set f = 16t + 4g + r)
    float wsig[8], b2r[8];
    #pragma unroll
    for (int t = 0; t < 2; ++t)
        #pragma unroll
        for (int r = 0; r < 4; ++r) {
            wsig[t*4+r] = w_sigma[t*16 + 4*g + r];
            b2r[t*4+r]  = b2[t*16 + 4*g + r];
        }
    const float bsig  = b_sigma[0];
    const float br2_0 = b_rgb2[0], br2_1 = b_rgb2[1], br2_2 = b_rgb2[2];

    const f32x4 zero4 = {0.f, 0.f, 0.f, 0.f};
    const int n_waves = (gridDim.x * blockDim.x) >> 6;
    const int wgid    = (blockIdx.x * blockDim.x + threadIdx.x) >> 6;

    for (int tile = wgid; tile < N_SAMPLES/16; tile += n_waves) {
        const int base = tile * 16;
        float p0=0,p1=0,p2=0,dx=0,dy=0,dz=0,dt=0;
        if (g == 0) {
            const float* s = samples + (size_t)(base + sl) * 7;
            p0=s[0]; p1=s[1]; p2=s[2]; dx=s[3]; dy=s[4]; dz=s[5]; dt=s[6];
        }
        // B1 = posaug: k0..2 = pos, k3 = 1 (bias)
        FragU b1u;
        b1u.w[0] = cvt_pk_bf16(p0, p1);
        b1u.w[1] = cvt_pk_bf16(p2, (g==0) ? 1.0f : 0.0f);
        b1u.w[2] = 0; b1u.w[3] = 0;

        // -------- layer1: h1 = relu(w1aug^T . posaug) --------
        f32x4 accL1[4];
        #pragma unroll
        for (int t = 0; t < 4; ++t)
            accL1[t] = __builtin_amdgcn_mfma_f32_16x16x32_bf16(A1[t], b1u.v, zero4, 0,0,0);

        asm volatile("s_waitcnt lgkmcnt(0)" ::: "memory");
        #pragma unroll
        for (int t = 0; t < 4; ++t) {   // write h1 (bf16) row=sl, j=16t+4g+r
            uint2 wv;
            wv.x = cvt_pk_bf16(fmaxf(accL1[t][0],0.f), fmaxf(accL1[t][1],0.f));
            wv.y = cvt_pk_bf16(fmaxf(accL1[t][2],0.f), fmaxf(accL1[t][3],0.f));
            const int gr = 2*t + (g>>1);
            *(uint2*)(hbuf + sl*128 + ((gr ^ (sl&7))<<4) + 8*(g&1)) = wv;
        }
        asm volatile("s_waitcnt lgkmcnt(0)" ::: "memory");

        // -------- layer2: feats = w2^T . h1 + b2 --------
        bf16x8 B2c[2];
        #pragma unroll
        for (int c = 0; c < 2; ++c)
            B2c[c] = *(const bf16x8*)(hbuf + sl*128 + (((4*c + g) ^ (sl&7))<<4));
        f32x4 accL2[2];
        #pragma unroll
        for (int t = 0; t < 2; ++t) {
            accL2[t] = __builtin_amdgcn_mfma_f32_16x16x32_bf16(A2[t][0], B2c[0], zero4, 0,0,0);
            accL2[t] = __builtin_amdgcn_mfma_f32_16x16x32_bf16(A2[t][1], B2c[1], accL2[t], 0,0,0);
        }
        float fF[8];
        #pragma unroll
        for (int t = 0; t < 2; ++t) {
            #pragma unroll
            for (int r = 0; r < 4; ++r) fF[t*4+r] = accL2[t][r] + b2r[t*4+r];
            uint2 wv;
            wv.x = cvt_pk_bf16(fF[t*4+0], fF[t*4+1]);
            wv.y = cvt_pk_bf16(fF[t*4+2], fF[t*4+3]);
            const int gr = 2*t + (g>>1);
            *(uint2*)(fbuf + sl*64 + ((gr ^ (sl&3))<<4) + 8*(g&1)) = wv;
        }
        // -------- sigma (fp32) --------
        float sp = 0.f;
        #pragma unroll
        for (int i = 0; i < 8; ++i) sp = fmaf(fF[i], wsig[i], sp);
        sp += __shfl_xor(sp, 16, 64);
        sp += __shfl_xor(sp, 32, 64);
        sp += bsig;
        const float sigma = fmaxf(sp, 0.f) + log1pf(expf(-fabsf(sp)));
        const float tau = sigma * dt;

        asm volatile("s_waitcnt lgkmcnt(0)" ::: "memory");
        // -------- rgb1: h = relu(w_rgb1^T . [feats; dirs; 1]) --------
        bf16x8 Bf = *(const bf16x8*)(fbuf + sl*64 + ((g ^ (sl&3))<<4));
        FragU bd;
        bd.w[0] = cvt_pk_bf16(dx, dy);
        bd.w[1] = cvt_pk_bf16(dz, (g==0) ? 1.0f : 0.0f);
        bd.w[2] = 0; bd.w[3] = 0;
        f32x4 ah[4];
        #pragma unroll
        for (int t = 0; t < 4; ++t) {
            ah[t] = __builtin_amdgcn_mfma_f32_16x16x32_bf16(Ar1a[t], Bf, zero4, 0,0,0);
            ah[t] = __builtin_amdgcn_mfma_f32_16x16x32_bf16(Ar1b[t], bd.v, ah[t], 0,0,0);
        }
        #pragma unroll
        for (int t = 0; t < 4; ++t) {   // write h (bf16), same geometry as h1
            uint2 wv;
            wv.x = cvt_pk_bf16(fmaxf(ah[t][0],0.f), fmaxf(ah[t][1],0.f));
            wv.y = cvt_pk_bf16(fmaxf(ah[t][2],0.f), fmaxf(ah[t][3],0.f));
            const int gr = 2*t + (g>>1);
            *(uint2*)(hbuf + sl*128 + ((gr ^ (sl&7))<<4) + 8*(g&1)) = wv;
        }
        asm volatile("s_waitcnt lgkmcnt(0)" ::: "memory");

        // -------- rgb2: rgb = sigmoid(w_rgb2^T . h + b) --------
        bf16x8 Bh[2];
        #pragma unroll
        for (int c = 0; c < 2; ++c)
            Bh[c] = *(const bf16x8*)(hbuf + sl*128 + (((4*c + g) ^ (sl&7))<<4));
        f32x4 ar;
        ar = __builtin_amdgcn_mfma_f32_16x16x32_bf16(Ar2[0], Bh[0], zero4, 0,0,0);
        ar = __builtin_amdgcn_mfma_f32_16x16x32_bf16(Ar2[1], Bh[1], ar, 0,0,0);

        const float rr = 1.f/(1.f + expf(-(ar[0] + br2_0)));
        const float gg = 1.f/(1.f + expf(-(ar[1] + br2_1)));
        const float bb = 1.f/(1.f + expf(-(ar[2] + br2_2)));

        if (g == 0) out[base + sl] = make_float4(tau, rr, gg, bb);
    }
}

// ---------------------------------------------------------------------------
// Kernel 2: one wave per ray — scan tau, gate, reduce (unchanged, passing).
// ---------------------------------------------------------------------------
__global__ __launch_bounds__(256) void nerf_render_kernel(
    const float4* __restrict__ smp,
    const int*    __restrict__ packing,
    const float*  __restrict__ bg,
    float*        __restrict__ out)
{
    const int gtid = blockIdx.x * blockDim.x + threadIdx.x;
    const int ray  = gtid >> 6;
    const int lane = threadIdx.x & 63;
    if (ray >= N_RAYS) return;

    const int start = packing[2 * ray];
    const int count = packing[2 * ray + 1];

    float tau = 0.0f, r = 0.0f, g = 0.0f, b = 0.0f;
    if (lane < count) {
        const float4 v = smp[start + lane];
        tau = v.x; r = v.y; g = v.z; b = v.w;
    }

    float incl = tau;
    #pragma unroll
    for (int off = 1; off < 64; off <<= 1) {
        const float v = __shfl_up(incl, off, 64);
        if (lane >= off) incl += v;
    }
    const float c_excl = incl - tau;

    const float T     = expf(-c_excl);
    const float alpha = 1.0f - expf(-tau);
    float w = (lane < count && T > THRESH) ? T * alpha : 0.0f;

    float cr = r * w, cg = g * w, cb = b * w;

    #pragma unroll
    for (int off = 32; off > 0; off >>= 1) {
        cr += __shfl_down(cr, off, 64);
        cg += __shfl_down(cg, off, 64);
        cb += __shfl_down(cb, off, 64);
        w  += __shfl_down(w,  off, 64);
    }

    if (lane == 0) {
        out[ray * 3 + 0] = cr + bg[0] * (1.0f - w);
        out[ray * 3 + 1] = cg + bg[1] * (1.0f - w);
        out[ray * 3 + 2] = cb + bg[2] * (1.0f - w);
    }
}

extern "C" void kernel_launch(void* const* d_in, const int* in_sizes, int n_in,
                              void* d_out, int out_size, void* d_ws, size_t ws_size,
                              hipStream_t stream) {
    const float* samples  = (const float*)d_in[0];
    const int*   packing  = (const int*)  d_in[1];
    const float* w1       = (const float*)d_in[3];
    const float* b1       = (const float*)d_in[4];
    const float* w2       = (const float*)d_in[5];
    const float* b2       = (const float*)d_in[6];
    const float* w_sigma  = (const float*)d_in[7];
    const float* b_sigma  = (const float*)d_in[8];
    const float* w_rgb1   = (const float*)d_in[9];
    const float* b_rgb1   = (const float*)d_in[10];
    const float* w_rgb2   = (const float*)d_in[11];
    const float* b_rgb2   = (const float*)d_in[12];
    const float* bg       = (const float*)d_in[13];

    float4* smp = (float4*)d_ws;     // N_SAMPLES * 16 B = 16 MiB
    float*  out = (float*)d_out;

    nerf_mlp_mfma<<<2048, 256, 0, stream>>>(
        samples, w1, b1, w2, b2, w_sigma, b_sigma,
        w_rgb1, b_rgb1, w_rgb2, b_rgb2, smp);

    nerf_render_kernel<<<(N_RAYS * 64) / 256, 256, 0, stream>>>(smp, packing, bg, out);
}

// Round 3
// 65.768 us; speedup vs baseline: 2.2259x; 1.1122x over previous
//
#include <hip/hip_runtime.h>
#include <math.h>
#include <stdint.h>

#define N_RAYS    32768
#define N_SAMPLES (N_RAYS * 32)
#define THRESH 0.0001f

typedef __attribute__((ext_vector_type(8))) __bf16 bf16x8;
typedef __attribute__((ext_vector_type(4))) float  f32x4;

union FragU { uint32_t w[4]; bf16x8 v; uint2 d[2]; };

__device__ inline uint32_t cvt_pk_bf16(float lo, float hi) {
    uint32_t r;
    asm("v_cvt_pk_bf16_f32 %0, %1, %2" : "=v"(r) : "v"(lo), "v"(hi));
    return r;
}

__device__ inline bf16x8 pack8(const float* vals) {
    FragU u;
    u.w[0] = cvt_pk_bf16(vals[0], vals[1]);
    u.w[1] = cvt_pk_bf16(vals[2], vals[3]);
    u.w[2] = cvt_pk_bf16(vals[4], vals[5]);
    u.w[3] = cvt_pk_bf16(vals[6], vals[7]);
    return u.v;
}

__device__ inline float rcp_fast(float x) {
    float r;
    asm("v_rcp_f32 %0, %1" : "=v"(r) : "v"(x));
    return r;
}
__device__ inline float sigmoid_fast(float x) {        // 1/(1+e^-x)
    return rcp_fast(1.0f + __expf(-x));
}
__device__ inline float softplus_fast(float x) {       // max(x,0)+log1p(e^-|x|)
    const float e = __expf(-fabsf(x));
    return fmaxf(x, 0.0f) + __logf(1.0f + e);
}

// ---------------------------------------------------------------------------
// MFMA MLP: one wave = 16 samples (sample on lane&15 = N axis everywhere).
// D layout (verified): n = lane&15, m = 4*(lane>>4) + reg.
// A/B k-slot convention (self-consistent): slot (g=lane>>4, reg r) <-> k=32*kstep+8g+r.
// sigma folded into rgb2 as row m=3 over a 3rd (feats) kstep.
// Next tile's samples are prefetched (double-buffered) to hide HBM latency.
// ---------------------------------------------------------------------------
__global__ __launch_bounds__(256, 4) void nerf_mlp_mfma(
    const float* __restrict__ samples,   // (N_SAMPLES, 7)
    const float* __restrict__ w1,        // (3, 64)
    const float* __restrict__ b1,        // (64)
    const float* __restrict__ w2,        // (64, 32)
    const float* __restrict__ b2,        // (32)
    const float* __restrict__ w_sigma,   // (32, 1)
    const float* __restrict__ b_sigma,   // (1)
    const float* __restrict__ w_rgb1,    // (35, 64)
    const float* __restrict__ b_rgb1,    // (64)
    const float* __restrict__ w_rgb2,    // (64, 3)
    const float* __restrict__ b_rgb2,    // (3)
    float4* __restrict__ out)            // (N_SAMPLES): tau, r, g, b
{
    __shared__ __align__(16) char lds_all[4][3072];
    const int wid  = threadIdx.x >> 6;
    const int lane = threadIdx.x & 63;
    const int g    = lane >> 4;
    const int sl   = lane & 15;
    char* hbuf = lds_all[wid];           // 16 rows x 128 B (64 bf16): h1 then h
    char* fbuf = lds_all[wid] + 2048;    // 16 rows x  64 B (32 bf16): feats

    const int n_waves = (gridDim.x * blockDim.x) >> 6;
    const int wgid    = (blockIdx.x * blockDim.x + threadIdx.x) >> 6;
    const int NT      = N_SAMPLES / 16;

    // ---- issue first tile's sample loads ASAP (latency hides under frag build)
    float cur[7] = {0,0,0,0,0,0,0};
    if (g == 0 && wgid < NT) {
        const float* s = samples + (size_t)(wgid * 16 + sl) * 7;
        #pragma unroll
        for (int i = 0; i < 7; ++i) cur[i] = s[i];
    }

    // ---------------- hoisted weight fragments (per wave) ----------------
    bf16x8 A1[4], A2[2][2], Ar1a[4], Ar1b[4], Ar2[2], Ar2f;

    #pragma unroll
    for (int t = 0; t < 4; ++t) {        // A1 = [w1;b1]^T, k:0..2=w1 rows, 3=b1
        float v[8] = {0,0,0,0,0,0,0,0};
        if (g == 0) {
            const int j = t*16 + sl;
            v[0] = w1[j]; v[1] = w1[64+j]; v[2] = w1[128+j]; v[3] = b1[j];
        }
        A1[t] = pack8(v);
    }
    #pragma unroll
    for (int t = 0; t < 2; ++t)          // A2 = w2^T (32x64), 2 ksteps
        #pragma unroll
        for (int c = 0; c < 2; ++c) {
            float v[8];
            #pragma unroll
            for (int r = 0; r < 8; ++r)
                v[r] = w2[(32*c + 8*g + r)*32 + t*16 + sl];
            A2[t][c] = pack8(v);
        }
    #pragma unroll
    for (int t = 0; t < 4; ++t) {        // Ar1a = w_rgb1^T rows 0..31 (feats)
        float v[8];
        #pragma unroll
        for (int r = 0; r < 8; ++r)
            v[r] = w_rgb1[(8*g + r)*64 + t*16 + sl];
        Ar1a[t] = pack8(v);
    }
    #pragma unroll
    for (int t = 0; t < 4; ++t) {        // Ar1b = dirs rows + b_rgb1 aug
        float v[8] = {0,0,0,0,0,0,0,0};
        if (g == 0) {
            const int j = t*16 + sl;
            v[0] = w_rgb1[32*64 + j]; v[1] = w_rgb1[33*64 + j];
            v[2] = w_rgb1[34*64 + j]; v[3] = b_rgb1[j];
        }
        Ar1b[t] = pack8(v);
    }
    #pragma unroll
    for (int c = 0; c < 2; ++c) {        // Ar2 = w_rgb2^T (rows 0..2), h ksteps
        float v[8];
        #pragma unroll
        for (int r = 0; r < 8; ++r)
            v[r] = (sl < 3) ? w_rgb2[(32*c + 8*g + r)*3 + sl] : 0.0f;
        Ar2[c] = pack8(v);
    }
    {                                    // Ar2f = w_sigma on row m=3, feats kstep
        float v[8];
        #pragma unroll
        for (int r = 0; r < 8; ++r)
            v[r] = (sl == 3) ? w_sigma[8*g + r] : 0.0f;
        Ar2f = pack8(v);
    }
    float b2r[8];                        // b2 for this lane's feat rows
    #pragma unroll
    for (int t = 0; t < 2; ++t)
        #pragma unroll
        for (int r = 0; r < 4; ++r)
            b2r[t*4+r] = b2[t*16 + 4*g + r];
    const float bsig  = b_sigma[0];
    const float br2_0 = b_rgb2[0], br2_1 = b_rgb2[1], br2_2 = b_rgb2[2];

    const f32x4 zero4 = {0.f, 0.f, 0.f, 0.f};

    for (int tile = wgid; tile < NT; tile += n_waves) {
        // ---- prefetch next tile's samples (issue now, consume at loop bottom)
        float nxt[7];
        const int tn = tile + n_waves;
        if (g == 0 && tn < NT) {
            const float* s = samples + (size_t)(tn * 16 + sl) * 7;
            #pragma unroll
            for (int i = 0; i < 7; ++i) nxt[i] = s[i];
        }

        const float p0 = cur[0], p1 = cur[1], p2 = cur[2];
        const float dx = cur[3], dy = cur[4], dz = cur[5];
        const float dt = cur[6];

        // B1 = posaug: k0..2 = pos, k3 = 1 (bias slot)
        FragU b1u;
        b1u.w[0] = cvt_pk_bf16(p0, p1);
        b1u.w[1] = cvt_pk_bf16(p2, (g==0) ? 1.0f : 0.0f);
        b1u.w[2] = 0; b1u.w[3] = 0;

        // -------- layer1: h1 = relu(w1aug^T . posaug) --------
        f32x4 accL1[4];
        #pragma unroll
        for (int t = 0; t < 4; ++t)
            accL1[t] = __builtin_amdgcn_mfma_f32_16x16x32_bf16(A1[t], b1u.v, zero4, 0,0,0);

        asm volatile("s_waitcnt lgkmcnt(0)" ::: "memory");
        #pragma unroll
        for (int t = 0; t < 4; ++t) {    // h1 (bf16): row=sl, j=16t+4g+r
            uint2 wv;
            wv.x = cvt_pk_bf16(fmaxf(accL1[t][0],0.f), fmaxf(accL1[t][1],0.f));
            wv.y = cvt_pk_bf16(fmaxf(accL1[t][2],0.f), fmaxf(accL1[t][3],0.f));
            const int gr = 2*t + (g>>1);
            *(uint2*)(hbuf + sl*128 + ((gr ^ (sl&7))<<4) + 8*(g&1)) = wv;
        }
        asm volatile("s_waitcnt lgkmcnt(0)" ::: "memory");

        // -------- layer2: feats = w2^T . h1 + b2 --------
        bf16x8 B2c[2];
        #pragma unroll
        for (int c = 0; c < 2; ++c)
            B2c[c] = *(const bf16x8*)(hbuf + sl*128 + (((4*c + g) ^ (sl&7))<<4));
        f32x4 accL2[2];
        #pragma unroll
        for (int t = 0; t < 2; ++t) {
            accL2[t] = __builtin_amdgcn_mfma_f32_16x16x32_bf16(A2[t][0], B2c[0], zero4, 0,0,0);
            accL2[t] = __builtin_amdgcn_mfma_f32_16x16x32_bf16(A2[t][1], B2c[1], accL2[t], 0,0,0);
        }
        #pragma unroll
        for (int t = 0; t < 2; ++t) {    // feats + b2 -> fbuf (bf16)
            uint2 wv;
            wv.x = cvt_pk_bf16(accL2[t][0] + b2r[t*4+0], accL2[t][1] + b2r[t*4+1]);
            wv.y = cvt_pk_bf16(accL2[t][2] + b2r[t*4+2], accL2[t][3] + b2r[t*4+3]);
            const int gr = 2*t + (g>>1);
            *(uint2*)(fbuf + sl*64 + ((gr ^ (sl&3))<<4) + 8*(g&1)) = wv;
        }
        asm volatile("s_waitcnt lgkmcnt(0)" ::: "memory");

        // -------- rgb1: h = relu(w_rgb1^T . [feats; dirs; 1]) --------
        bf16x8 Bf = *(const bf16x8*)(fbuf + sl*64 + ((g ^ (sl&3))<<4));
        FragU bd;
        bd.w[0] = cvt_pk_bf16(dx, dy);
        bd.w[1] = cvt_pk_bf16(dz, (g==0) ? 1.0f : 0.0f);
        bd.w[2] = 0; bd.w[3] = 0;
        f32x4 ah[4];
        #pragma unroll
        for (int t = 0; t < 4; ++t) {
            ah[t] = __builtin_amdgcn_mfma_f32_16x16x32_bf16(Ar1a[t], Bf, zero4, 0,0,0);
            ah[t] = __builtin_amdgcn_mfma_f32_16x16x32_bf16(Ar1b[t], bd.v, ah[t], 0,0,0);
        }
        #pragma unroll
        for (int t = 0; t < 4; ++t) {    // h (bf16), same geometry as h1
            uint2 wv;
            wv.x = cvt_pk_bf16(fmaxf(ah[t][0],0.f), fmaxf(ah[t][1],0.f));
            wv.y = cvt_pk_bf16(fmaxf(ah[t][2],0.f), fmaxf(ah[t][3],0.f));
            const int gr = 2*t + (g>>1);
            *(uint2*)(hbuf + sl*128 + ((gr ^ (sl&7))<<4) + 8*(g&1)) = wv;
        }
        asm volatile("s_waitcnt lgkmcnt(0)" ::: "memory");

        // -------- rgb2 (+sigma row): [r,g,b,sp] = A . [h; feats] --------
        bf16x8 Bh[2];
        #pragma unroll
        for (int c = 0; c < 2; ++c)
            Bh[c] = *(const bf16x8*)(hbuf + sl*128 + (((4*c + g) ^ (sl&7))<<4));
        f32x4 ar;
        ar = __builtin_amdgcn_mfma_f32_16x16x32_bf16(Ar2[0], Bh[0], zero4, 0,0,0);
        ar = __builtin_amdgcn_mfma_f32_16x16x32_bf16(Ar2[1], Bh[1], ar, 0,0,0);
        ar = __builtin_amdgcn_mfma_f32_16x16x32_bf16(Ar2f,   Bf,    ar, 0,0,0);

        const float rr    = sigmoid_fast(ar[0] + br2_0);
        const float gg    = sigmoid_fast(ar[1] + br2_1);
        const float bb    = sigmoid_fast(ar[2] + br2_2);
        const float sigma = softplus_fast(ar[3] + bsig);
        const float tau   = sigma * dt;

        if (g == 0) out[tile * 16 + sl] = make_float4(tau, rr, gg, bb);

        #pragma unroll
        for (int i = 0; i < 7; ++i) cur[i] = nxt[i];
    }
}

// ---------------------------------------------------------------------------
// Kernel 2: one wave per ray — scan tau, gate, reduce.
// ---------------------------------------------------------------------------
__global__ __launch_bounds__(256) void nerf_render_kernel(
    const float4* __restrict__ smp,
    const int*    __restrict__ packing,
    const float*  __restrict__ bg,
    float*        __restrict__ out)
{
    const int gtid = blockIdx.x * blockDim.x + threadIdx.x;
    const int ray  = gtid >> 6;
    const int lane = threadIdx.x & 63;
    if (ray >= N_RAYS) return;

    const int start = packing[2 * ray];
    const int count = packing[2 * ray + 1];

    float tau = 0.0f, r = 0.0f, g = 0.0f, b = 0.0f;
    if (lane < count) {
        const float4 v = smp[start + lane];
        tau = v.x; r = v.y; g = v.z; b = v.w;
    }

    float incl = tau;
    #pragma unroll
    for (int off = 1; off < 64; off <<= 1) {
        const float v = __shfl_up(incl, off, 64);
        if (lane >= off) incl += v;
    }
    const float c_excl = incl - tau;

    const float T     = __expf(-c_excl);
    const float alpha = 1.0f - __expf(-tau);
    float w = (lane < count && T > THRESH) ? T * alpha : 0.0f;

    float cr = r * w, cg = g * w, cb = b * w;

    #pragma unroll
    for (int off = 32; off > 0; off >>= 1) {
        cr += __shfl_down(cr, off, 64);
        cg += __shfl_down(cg, off, 64);
        cb += __shfl_down(cb, off, 64);
        w  += __shfl_down(w,  off, 64);
    }

    if (lane == 0) {
        out[ray * 3 + 0] = cr + bg[0] * (1.0f - w);
        out[ray * 3 + 1] = cg + bg[1] * (1.0f - w);
        out[ray * 3 + 2] = cb + bg[2] * (1.0f - w);
    }
}

extern "C" void kernel_launch(void* const* d_in, const int* in_sizes, int n_in,
                              void* d_out, int out_size, void* d_ws, size_t ws_size,
                              hipStream_t stream) {
    const float* samples  = (const float*)d_in[0];
    const int*   packing  = (const int*)  d_in[1];
    const float* w1       = (const float*)d_in[3];
    const float* b1       = (const float*)d_in[4];
    const float* w2       = (const float*)d_in[5];
    const float* b2       = (const float*)d_in[6];
    const float* w_sigma  = (const float*)d_in[7];
    const float* b_sigma  = (const float*)d_in[8];
    const float* w_rgb1   = (const float*)d_in[9];
    const float* b_rgb1   = (const float*)d_in[10];
    const float* w_rgb2   = (const float*)d_in[11];
    const float* b_rgb2   = (const float*)d_in[12];
    const float* bg       = (const float*)d_in[13];

    float4* smp = (float4*)d_ws;     // N_SAMPLES * 16 B = 16 MiB
    float*  out = (float*)d_out;

    nerf_mlp_mfma<<<4096, 256, 0, stream>>>(
        samples, w1, b1, w2, b2, w_sigma, b_sigma,
        w_rgb1, b_rgb1, w_rgb2, b_rgb2, smp);

    nerf_render_kernel<<<(N_RAYS * 64) / 256, 256, 0, stream>>>(smp, packing, bg, out);
}

// Round 5
// 58.718 us; speedup vs baseline: 2.4931x; 1.1201x over previous
//
#include <hip/hip_runtime.h>
#include <hip/hip_bf16.h>
#include <math.h>
#include <stdint.h>

#define N_RAYS    32768
#define N_SAMPLES (N_RAYS * 32)
#define THRESH 0.0001f

typedef __attribute__((ext_vector_type(8))) __bf16 bf16x8;
typedef __attribute__((ext_vector_type(4))) float  f32x4;

union FragU { __hip_bfloat162 h2[4]; uint32_t w[4]; bf16x8 v; };

// compiler-modeled packed f32->bf16 (emits v_cvt_pk_bf16_f32 WITH hazard handling;
// round-4's inline-asm version fed MFMA operands directly and produced garbage —
// inline asm is opaque to the AMDGPU hazard recognizer)
__device__ inline __hip_bfloat162 pk2(float lo, float hi) {
    float2 t; t.x = lo; t.y = hi;
    return __float22bfloat162_rn(t);
}

__device__ inline bf16x8 pack8(const float* vals) {
    FragU u;
    u.h2[0] = pk2(vals[0], vals[1]);
    u.h2[1] = pk2(vals[2], vals[3]);
    u.h2[2] = pk2(vals[4], vals[5]);
    u.h2[3] = pk2(vals[6], vals[7]);
    return u.v;
}

__device__ inline float rcp_fast(float x) {
    float r;
    asm("v_rcp_f32 %0, %1" : "=v"(r) : "v"(x));
    return r;
}
__device__ inline float sigmoid_fast(float x) { return rcp_fast(1.0f + __expf(-x)); }
__device__ inline float softplus_fast(float x) {
    const float e = __expf(-fabsf(x));
    return fmaxf(x, 0.0f) + __logf(1.0f + e);
}

// ---------------------------------------------------------------------------
// Pure-register MFMA MLP: one wave = 16 samples (sample on lane&15 = N axis).
// D layout (verified): n = lane&15, m = 4*(lane>>4) + reg.
// The k-slot ordering inside an MFMA fragment is a free convention as long as
// A and B agree (round-3 pass proves HW s_A == s_B). We pick the B k-mapping
// of each layer to equal the PREVIOUS layer's D register layout:
//   slot (g, q) <-> j = 16*(2c + (q>>2)) + 4*g + (q&3)
// so B_next = cvt_pk(relu(acc_prev)) in-lane: NO LDS, no cross-lane moves.
// sigma rides rgb2's MFMA as row m=3 over an extra feats kstep.
// ---------------------------------------------------------------------------
__global__ __launch_bounds__(256, 2) void nerf_mlp_mfma(
    const float* __restrict__ samples,   // (N_SAMPLES, 7)
    const float* __restrict__ w1,        // (3, 64)
    const float* __restrict__ b1,        // (64)
    const float* __restrict__ w2,        // (64, 32)
    const float* __restrict__ b2,        // (32)
    const float* __restrict__ w_sigma,   // (32, 1)
    const float* __restrict__ b_sigma,   // (1)
    const float* __restrict__ w_rgb1,    // (35, 64)
    const float* __restrict__ b_rgb1,    // (64)
    const float* __restrict__ w_rgb2,    // (64, 3)
    const float* __restrict__ b_rgb2,    // (3)
    float4* __restrict__ out)            // (N_SAMPLES): tau, r, g, b
{
    const int lane = threadIdx.x & 63;
    const int g    = lane >> 4;
    const int sl   = lane & 15;

    const int n_waves = (gridDim.x * blockDim.x) >> 6;
    const int wgid    = (blockIdx.x * blockDim.x + threadIdx.x) >> 6;
    const int NT      = N_SAMPLES / 16;

    // ---- issue first tile's sample loads ASAP
    float cur[7] = {0,0,0,0,0,0,0};
    if (g == 0 && wgid < NT) {
        const float* s = samples + (size_t)(wgid * 16 + sl) * 7;
        #pragma unroll
        for (int i = 0; i < 7; ++i) cur[i] = s[i];
    }

    // ---------------- weight fragments (permuted k-indexing) ----------------
    bf16x8 A1[4], A2[2][2], Ar1a[4], Ar1b[4], Ar2[2], Ar2f;

    #pragma unroll
    for (int t = 0; t < 4; ++t) {        // A1 = [w1;b1]^T; B1 k-slots: g==0, q=0..3
        float v[8] = {0,0,0,0,0,0,0,0};
        if (g == 0) {
            const int j = t*16 + sl;
            v[0] = w1[j]; v[1] = w1[64+j]; v[2] = w1[128+j]; v[3] = b1[j];
        }
        A1[t] = pack8(v);
    }
    #pragma unroll
    for (int t = 0; t < 2; ++t)          // A2 = w2^T; k-slot q <-> h1 index j(c,g,q)
        #pragma unroll
        for (int c = 0; c < 2; ++c) {
            float v[8];
            #pragma unroll
            for (int q = 0; q < 8; ++q) {
                const int j = 16*(2*c + (q>>2)) + 4*g + (q&3);
                v[q] = w2[j*32 + t*16 + sl];
            }
            A2[t][c] = pack8(v);
        }
    #pragma unroll
    for (int t = 0; t < 4; ++t) {        // Ar1a = w_rgb1^T (feats); f(g,q)
        float v[8];
        #pragma unroll
        for (int q = 0; q < 8; ++q) {
            const int f = 16*(q>>2) + 4*g + (q&3);
            v[q] = w_rgb1[f*64 + t*16 + sl];
        }
        Ar1a[t] = pack8(v);
    }
    #pragma unroll
    for (int t = 0; t < 4; ++t) {        // Ar1b = dirs rows + b_rgb1 aug (g==0 slots)
        float v[8] = {0,0,0,0,0,0,0,0};
        if (g == 0) {
            const int j = t*16 + sl;
            v[0] = w_rgb1[32*64 + j]; v[1] = w_rgb1[33*64 + j];
            v[2] = w_rgb1[34*64 + j]; v[3] = b_rgb1[j];
        }
        Ar1b[t] = pack8(v);
    }
    #pragma unroll
    for (int c = 0; c < 2; ++c) {        // Ar2 = w_rgb2^T rows m=0..2; k <-> hh(c,g,q)
        float v[8];
        #pragma unroll
        for (int q = 0; q < 8; ++q) {
            const int hh = 16*(2*c + (q>>2)) + 4*g + (q&3);
            v[q] = (sl < 3) ? w_rgb2[hh*3 + sl] : 0.0f;
        }
        Ar2[c] = pack8(v);
    }
    {                                    // Ar2f = w_sigma on row m=3, feats kstep
        float v[8];
        #pragma unroll
        for (int q = 0; q < 8; ++q) {
            const int f = 16*(q>>2) + 4*g + (q&3);
            v[q] = (sl == 3) ? w_sigma[f] : 0.0f;
        }
        Ar2f = pack8(v);
    }
    float b2r[8];                        // b2 for this lane's feat slots q
    #pragma unroll
    for (int q = 0; q < 8; ++q)
        b2r[q] = b2[16*(q>>2) + 4*g + (q&3)];
    const float bsig  = b_sigma[0];
    const float br2_0 = b_rgb2[0], br2_1 = b_rgb2[1], br2_2 = b_rgb2[2];

    const f32x4 zero4 = {0.f, 0.f, 0.f, 0.f};

    for (int tile = wgid; tile < NT; tile += n_waves) {
        // ---- prefetch next tile's samples (consume at loop bottom)
        float nxt[7] = {0,0,0,0,0,0,0};
        const int tn = tile + n_waves;
        if (g == 0 && tn < NT) {
            const float* s = samples + (size_t)(tn * 16 + sl) * 7;
            #pragma unroll
            for (int i = 0; i < 7; ++i) nxt[i] = s[i];
        }

        const float p0 = cur[0], p1 = cur[1], p2 = cur[2];
        const float dx = cur[3], dy = cur[4], dz = cur[5];
        const float dt = cur[6];

        // B1 = posaug (g==0 slots): k0..2 = pos, k3 = 1
        FragU b1u;
        b1u.h2[0] = pk2(p0, p1);
        b1u.h2[1] = pk2(p2, (g==0) ? 1.0f : 0.0f);
        b1u.w[2] = 0; b1u.w[3] = 0;

        // -------- layer1: h1 = relu(w1aug^T . posaug) --------
        f32x4 accL1[4];
        #pragma unroll
        for (int t = 0; t < 4; ++t)
            accL1[t] = __builtin_amdgcn_mfma_f32_16x16x32_bf16(A1[t], b1u.v, zero4, 0,0,0);

        // B2 from accL1 in-register: slot q of kstep c = relu(accL1[2c+(q>>2)][q&3])
        FragU B2c[2];
        #pragma unroll
        for (int c = 0; c < 2; ++c) {
            B2c[c].h2[0] = pk2(fmaxf(accL1[2*c  ][0],0.f), fmaxf(accL1[2*c  ][1],0.f));
            B2c[c].h2[1] = pk2(fmaxf(accL1[2*c  ][2],0.f), fmaxf(accL1[2*c  ][3],0.f));
            B2c[c].h2[2] = pk2(fmaxf(accL1[2*c+1][0],0.f), fmaxf(accL1[2*c+1][1],0.f));
            B2c[c].h2[3] = pk2(fmaxf(accL1[2*c+1][2],0.f), fmaxf(accL1[2*c+1][3],0.f));
        }

        // -------- layer2: feats = w2^T . h1 + b2 --------
        f32x4 accL2[2];
        #pragma unroll
        for (int t = 0; t < 2; ++t) {
            accL2[t] = __builtin_amdgcn_mfma_f32_16x16x32_bf16(A2[t][0], B2c[0].v, zero4, 0,0,0);
            accL2[t] = __builtin_amdgcn_mfma_f32_16x16x32_bf16(A2[t][1], B2c[1].v, accL2[t], 0,0,0);
        }
        // Bf from accL2 + b2 in-register: slot q = accL2[q>>2][q&3] + b2r[q]
        float fF[8];
        #pragma unroll
        for (int q = 0; q < 8; ++q) fF[q] = accL2[q>>2][q&3] + b2r[q];
        FragU Bf;
        Bf.h2[0] = pk2(fF[0], fF[1]);
        Bf.h2[1] = pk2(fF[2], fF[3]);
        Bf.h2[2] = pk2(fF[4], fF[5]);
        Bf.h2[3] = pk2(fF[6], fF[7]);

        // bd = dirsaug (g==0 slots): k0..2 = dirs, k3 = 1
        FragU bd;
        bd.h2[0] = pk2(dx, dy);
        bd.h2[1] = pk2(dz, (g==0) ? 1.0f : 0.0f);
        bd.w[2] = 0; bd.w[3] = 0;

        // -------- rgb1: h = relu(w_rgb1^T . [feats; dirs; 1]) --------
        f32x4 ah[4];
        #pragma unroll
        for (int t = 0; t < 4; ++t) {
            ah[t] = __builtin_amdgcn_mfma_f32_16x16x32_bf16(Ar1a[t], Bf.v, zero4, 0,0,0);
            ah[t] = __builtin_amdgcn_mfma_f32_16x16x32_bf16(Ar1b[t], bd.v, ah[t], 0,0,0);
        }
        // Bh from ah in-register
        FragU Bh[2];
        #pragma unroll
        for (int c = 0; c < 2; ++c) {
            Bh[c].h2[0] = pk2(fmaxf(ah[2*c  ][0],0.f), fmaxf(ah[2*c  ][1],0.f));
            Bh[c].h2[1] = pk2(fmaxf(ah[2*c  ][2],0.f), fmaxf(ah[2*c  ][3],0.f));
            Bh[c].h2[2] = pk2(fmaxf(ah[2*c+1][0],0.f), fmaxf(ah[2*c+1][1],0.f));
            Bh[c].h2[3] = pk2(fmaxf(ah[2*c+1][2],0.f), fmaxf(ah[2*c+1][3],0.f));
        }

        // -------- rgb2 (+sigma row m=3): [r,g,b,sp] --------
        f32x4 ar;
        ar = __builtin_amdgcn_mfma_f32_16x16x32_bf16(Ar2[0], Bh[0].v, zero4, 0,0,0);
        ar = __builtin_amdgcn_mfma_f32_16x16x32_bf16(Ar2[1], Bh[1].v, ar, 0,0,0);
        ar = __builtin_amdgcn_mfma_f32_16x16x32_bf16(Ar2f,   Bf.v,    ar, 0,0,0);

        const float rr    = sigmoid_fast(ar[0] + br2_0);
        const float gg    = sigmoid_fast(ar[1] + br2_1);
        const float bb    = sigmoid_fast(ar[2] + br2_2);
        const float sigma = softplus_fast(ar[3] + bsig);
        const float tau   = sigma * dt;

        if (g == 0) out[tile * 16 + sl] = make_float4(tau, rr, gg, bb);

        #pragma unroll
        for (int i = 0; i < 7; ++i) cur[i] = nxt[i];
    }
}

// ---------------------------------------------------------------------------
// Kernel 2: one wave per ray — scan tau, gate, reduce.
// ---------------------------------------------------------------------------
__global__ __launch_bounds__(256) void nerf_render_kernel(
    const float4* __restrict__ smp,
    const int*    __restrict__ packing,
    const float*  __restrict__ bg,
    float*        __restrict__ out)
{
    const int gtid = blockIdx.x * blockDim.x + threadIdx.x;
    const int ray  = gtid >> 6;
    const int lane = threadIdx.x & 63;
    if (ray >= N_RAYS) return;

    const int start = packing[2 * ray];
    const int count = packing[2 * ray + 1];

    float tau = 0.0f, r = 0.0f, g = 0.0f, b = 0.0f;
    if (lane < count) {
        const float4 v = smp[start + lane];
        tau = v.x; r = v.y; g = v.z; b = v.w;
    }

    float incl = tau;
    #pragma unroll
    for (int off = 1; off < 64; off <<= 1) {
        const float v = __shfl_up(incl, off, 64);
        if (lane >= off) incl += v;
    }
    const float c_excl = incl - tau;

    const float T     = __expf(-c_excl);
    const float alpha = 1.0f - __expf(-tau);
    float w = (lane < count && T > THRESH) ? T * alpha : 0.0f;

    float cr = r * w, cg = g * w, cb = b * w;

    #pragma unroll
    for (int off = 32; off > 0; off >>= 1) {
        cr += __shfl_down(cr, off, 64);
        cg += __shfl_down(cg, off, 64);
        cb += __shfl_down(cb, off, 64);
        w  += __shfl_down(w,  off, 64);
    }

    if (lane == 0) {
        out[ray * 3 + 0] = cr + bg[0] * (1.0f - w);
        out[ray * 3 + 1] = cg + bg[1] * (1.0f - w);
        out[ray * 3 + 2] = cb + bg[2] * (1.0f - w);
    }
}

extern "C" void kernel_launch(void* const* d_in, const int* in_sizes, int n_in,
                              void* d_out, int out_size, void* d_ws, size_t ws_size,
                              hipStream_t stream) {
    const float* samples  = (const float*)d_in[0];
    const int*   packing  = (const int*)  d_in[1];
    const float* w1       = (const float*)d_in[3];
    const float* b1       = (const float*)d_in[4];
    const float* w2       = (const float*)d_in[5];
    const float* b2       = (const float*)d_in[6];
    const float* w_sigma  = (const float*)d_in[7];
    const float* b_sigma  = (const float*)d_in[8];
    const float* w_rgb1   = (const float*)d_in[9];
    const float* b_rgb1   = (const float*)d_in[10];
    const float* w_rgb2   = (const float*)d_in[11];
    const float* b_rgb2   = (const float*)d_in[12];
    const float* bg       = (const float*)d_in[13];

    float4* smp = (float4*)d_ws;     // N_SAMPLES * 16 B = 16 MiB
    float*  out = (float*)d_out;

    // 2048 blocks * 4 waves = 8192 waves; 8 tiles/wave; weight-frag build
    // amortized; enough resident waves (>=2-4/SIMD) to hide chain latency.
    nerf_mlp_mfma<<<2048, 256, 0, stream>>>(
        samples, w1, b1, w2, b2, w_sigma, b_sigma,
        w_rgb1, b_rgb1, w_rgb2, b_rgb2, smp);

    nerf_render_kernel<<<(N_RAYS * 64) / 256, 256, 0, stream>>>(smp, packing, bg, out);
}

// Round 6
// 54.880 us; speedup vs baseline: 2.6675x; 1.0699x over previous
//
#include <hip/hip_runtime.h>
#include <hip/hip_bf16.h>
#include <math.h>
#include <stdint.h>

#define N_RAYS    32768
#define N_SAMPLES (N_RAYS * 32)
#define THRESH 0.0001f

typedef __attribute__((ext_vector_type(8))) __bf16 bf16x8;
typedef __attribute__((ext_vector_type(4))) float  f32x4;

union FragU { __hip_bfloat162 h2[4]; uint32_t w[4]; bf16x8 v; };

// compiler-modeled packed f32->bf16 (hazard-safe v_cvt_pk_bf16_f32)
__device__ inline __hip_bfloat162 pk2(float lo, float hi) {
    float2 t; t.x = lo; t.y = hi;
    return __float22bfloat162_rn(t);
}

__device__ inline bf16x8 pack8(const float* vals) {
    FragU u;
    u.h2[0] = pk2(vals[0], vals[1]);
    u.h2[1] = pk2(vals[2], vals[3]);
    u.h2[2] = pk2(vals[4], vals[5]);
    u.h2[3] = pk2(vals[6], vals[7]);
    return u.v;
}

__device__ inline float rcp_fast(float x) {
    float r;
    asm("v_rcp_f32 %0, %1" : "=v"(r) : "v"(x));
    return r;
}
__device__ inline float sigmoid_fast(float x) { return rcp_fast(1.0f + __expf(-x)); }
__device__ inline float softplus_fast(float x) {
    const float e = __expf(-fabsf(x));
    return fmaxf(x, 0.0f) + __logf(1.0f + e);
}

// ---------------------------------------------------------------------------
// Pure-register MFMA MLP, 2 interleaved sample-tiles (32 samples) per wave
// iteration. Sample on lane&15 = N axis. D layout: n=lane&15, m=4*(lane>>4)+reg.
// B k-mapping of each layer == previous layer's D register layout:
//   slot (g, q) <-> j = 16*(2c + (q>>2)) + 4*g + (q&3)
// => B_next = cvt_pk(relu(acc_prev)) in-lane: no LDS, no cross-lane moves.
// Biases enter through the MFMA C-operand (C layout == D layout).
// sigma rides rgb2's MFMA as row m=3 over an extra feats kstep.
// ---------------------------------------------------------------------------
__global__ __launch_bounds__(256, 2) void nerf_mlp_mfma(
    const float* __restrict__ samples,   // (N_SAMPLES, 7)
    const float* __restrict__ w1,        // (3, 64)
    const float* __restrict__ b1,        // (64)
    const float* __restrict__ w2,        // (64, 32)
    const float* __restrict__ b2,        // (32)
    const float* __restrict__ w_sigma,   // (32, 1)
    const float* __restrict__ b_sigma,   // (1)
    const float* __restrict__ w_rgb1,    // (35, 64)
    const float* __restrict__ b_rgb1,    // (64)
    const float* __restrict__ w_rgb2,    // (64, 3)
    const float* __restrict__ b_rgb2,    // (3)
    float4* __restrict__ out)            // (N_SAMPLES): tau, r, g, b
{
    const int lane = threadIdx.x & 63;
    const int g    = lane >> 4;
    const int sl   = lane & 15;

    const int n_waves = (gridDim.x * blockDim.x) >> 6;
    const int wgid    = (blockIdx.x * blockDim.x + threadIdx.x) >> 6;
    const int NPAIR   = N_SAMPLES / 32;   // two 16-sample tiles per iteration

    // ---- first pair's sample loads issued ASAP
    float cur[2][7] = {{0,0,0,0,0,0,0},{0,0,0,0,0,0,0}};
    if (g == 0 && wgid < NPAIR) {
        const float* s0 = samples + (size_t)(wgid * 32 + sl) * 7;
        const float* s1 = s0 + 16 * 7;
        #pragma unroll
        for (int i = 0; i < 7; ++i) { cur[0][i] = s0[i]; cur[1][i] = s1[i]; }
    }

    // ---------------- weight fragments (permuted k-indexing) ----------------
    bf16x8 A1[4], A2[2][2], Ar1a[4], Ar1b[4], Ar2[2], Ar2f;

    #pragma unroll
    for (int t = 0; t < 4; ++t) {        // A1 = [w1;b1]^T; B1 k-slots: g==0, q=0..3
        float v[8] = {0,0,0,0,0,0,0,0};
        if (g == 0) {
            const int j = t*16 + sl;
            v[0] = w1[j]; v[1] = w1[64+j]; v[2] = w1[128+j]; v[3] = b1[j];
        }
        A1[t] = pack8(v);
    }
    #pragma unroll
    for (int t = 0; t < 2; ++t)          // A2 = w2^T; k-slot q <-> h1 index j(c,g,q)
        #pragma unroll
        for (int c = 0; c < 2; ++c) {
            float v[8];
            #pragma unroll
            for (int q = 0; q < 8; ++q) {
                const int j = 16*(2*c + (q>>2)) + 4*g + (q&3);
                v[q] = w2[j*32 + t*16 + sl];
            }
            A2[t][c] = pack8(v);
        }
    #pragma unroll
    for (int t = 0; t < 4; ++t) {        // Ar1a = w_rgb1^T (feats); f(g,q)
        float v[8];
        #pragma unroll
        for (int q = 0; q < 8; ++q) {
            const int f = 16*(q>>2) + 4*g + (q&3);
            v[q] = w_rgb1[f*64 + t*16 + sl];
        }
        Ar1a[t] = pack8(v);
    }
    #pragma unroll
    for (int t = 0; t < 4; ++t) {        // Ar1b = dirs rows + b_rgb1 aug (g==0 slots)
        float v[8] = {0,0,0,0,0,0,0,0};
        if (g == 0) {
            const int j = t*16 + sl;
            v[0] = w_rgb1[32*64 + j]; v[1] = w_rgb1[33*64 + j];
            v[2] = w_rgb1[34*64 + j]; v[3] = b_rgb1[j];
        }
        Ar1b[t] = pack8(v);
    }
    #pragma unroll
    for (int c = 0; c < 2; ++c) {        // Ar2 = w_rgb2^T rows m=0..2; k <-> hh(c,g,q)
        float v[8];
        #pragma unroll
        for (int q = 0; q < 8; ++q) {
            const int hh = 16*(2*c + (q>>2)) + 4*g + (q&3);
            v[q] = (sl < 3) ? w_rgb2[hh*3 + sl] : 0.0f;
        }
        Ar2[c] = pack8(v);
    }
    {                                    // Ar2f = w_sigma on row m=3, feats kstep
        float v[8];
        #pragma unroll
        for (int q = 0; q < 8; ++q) {
            const int f = 16*(q>>2) + 4*g + (q&3);
            v[q] = (sl == 3) ? w_sigma[f] : 0.0f;
        }
        Ar2f = pack8(v);
    }
    // bias C-inits (C layout == D layout: m = 4g + r)
    f32x4 b2i[2];
    #pragma unroll
    for (int t = 0; t < 2; ++t)
        #pragma unroll
        for (int r = 0; r < 4; ++r)
            b2i[t][r] = b2[16*t + 4*g + r];
    f32x4 arinit;
    arinit[0] = b_rgb2[0]; arinit[1] = b_rgb2[1];
    arinit[2] = b_rgb2[2]; arinit[3] = b_sigma[0];

    const f32x4 zero4 = {0.f, 0.f, 0.f, 0.f};

    for (int pair = wgid; pair < NPAIR; pair += n_waves) {
        // ---- prefetch next pair (consumed at loop bottom)
        float nxt[2][7] = {{0,0,0,0,0,0,0},{0,0,0,0,0,0,0}};
        const int tn = pair + n_waves;
        if (g == 0 && tn < NPAIR) {
            const float* s0 = samples + (size_t)(tn * 32 + sl) * 7;
            const float* s1 = s0 + 16 * 7;
            #pragma unroll
            for (int i = 0; i < 7; ++i) { nxt[0][i] = s0[i]; nxt[1][i] = s1[i]; }
        }

        // ---- input fragments for both streams
        FragU b1u[2], bd[2];
        #pragma unroll
        for (int s = 0; s < 2; ++s) {
            b1u[s].h2[0] = pk2(cur[s][0], cur[s][1]);
            b1u[s].h2[1] = pk2(cur[s][2], (g==0) ? 1.0f : 0.0f);
            b1u[s].w[2] = 0; b1u[s].w[3] = 0;
            bd[s].h2[0]  = pk2(cur[s][3], cur[s][4]);
            bd[s].h2[1]  = pk2(cur[s][5], (g==0) ? 1.0f : 0.0f);
            bd[s].w[2] = 0; bd[s].w[3] = 0;
        }

        // -------- layer1: h1 = relu(w1aug^T . posaug), 2 streams --------
        f32x4 accL1[2][4];
        #pragma unroll
        for (int t = 0; t < 4; ++t)
            #pragma unroll
            for (int s = 0; s < 2; ++s)
                accL1[s][t] = __builtin_amdgcn_mfma_f32_16x16x32_bf16(A1[t], b1u[s].v, zero4, 0,0,0);

        FragU B2c[2][2];
        #pragma unroll
        for (int s = 0; s < 2; ++s)
            #pragma unroll
            for (int c = 0; c < 2; ++c) {
                B2c[s][c].h2[0] = pk2(fmaxf(accL1[s][2*c  ][0],0.f), fmaxf(accL1[s][2*c  ][1],0.f));
                B2c[s][c].h2[1] = pk2(fmaxf(accL1[s][2*c  ][2],0.f), fmaxf(accL1[s][2*c  ][3],0.f));
                B2c[s][c].h2[2] = pk2(fmaxf(accL1[s][2*c+1][0],0.f), fmaxf(accL1[s][2*c+1][1],0.f));
                B2c[s][c].h2[3] = pk2(fmaxf(accL1[s][2*c+1][2],0.f), fmaxf(accL1[s][2*c+1][3],0.f));
            }

        // -------- layer2: feats = w2^T . h1 (+b2 via C-init) --------
        f32x4 accL2[2][2];
        #pragma unroll
        for (int t = 0; t < 2; ++t)
            #pragma unroll
            for (int s = 0; s < 2; ++s) {
                accL2[s][t] = __builtin_amdgcn_mfma_f32_16x16x32_bf16(A2[t][0], B2c[s][0].v, b2i[t], 0,0,0);
                accL2[s][t] = __builtin_amdgcn_mfma_f32_16x16x32_bf16(A2[t][1], B2c[s][1].v, accL2[s][t], 0,0,0);
            }
        FragU Bf[2];
        #pragma unroll
        for (int s = 0; s < 2; ++s) {
            Bf[s].h2[0] = pk2(accL2[s][0][0], accL2[s][0][1]);
            Bf[s].h2[1] = pk2(accL2[s][0][2], accL2[s][0][3]);
            Bf[s].h2[2] = pk2(accL2[s][1][0], accL2[s][1][1]);
            Bf[s].h2[3] = pk2(accL2[s][1][2], accL2[s][1][3]);
        }

        // -------- rgb1: h = relu(w_rgb1^T . [feats; dirs; 1]) --------
        f32x4 ah[2][4];
        #pragma unroll
        for (int t = 0; t < 4; ++t)
            #pragma unroll
            for (int s = 0; s < 2; ++s) {
                ah[s][t] = __builtin_amdgcn_mfma_f32_16x16x32_bf16(Ar1a[t], Bf[s].v, zero4, 0,0,0);
                ah[s][t] = __builtin_amdgcn_mfma_f32_16x16x32_bf16(Ar1b[t], bd[s].v, ah[s][t], 0,0,0);
            }
        FragU Bh[2][2];
        #pragma unroll
        for (int s = 0; s < 2; ++s)
            #pragma unroll
            for (int c = 0; c < 2; ++c) {
                Bh[s][c].h2[0] = pk2(fmaxf(ah[s][2*c  ][0],0.f), fmaxf(ah[s][2*c  ][1],0.f));
                Bh[s][c].h2[1] = pk2(fmaxf(ah[s][2*c  ][2],0.f), fmaxf(ah[s][2*c  ][3],0.f));
                Bh[s][c].h2[2] = pk2(fmaxf(ah[s][2*c+1][0],0.f), fmaxf(ah[s][2*c+1][1],0.f));
                Bh[s][c].h2[3] = pk2(fmaxf(ah[s][2*c+1][2],0.f), fmaxf(ah[s][2*c+1][3],0.f));
            }

        // -------- rgb2 (+sigma row m=3), biases via C-init --------
        f32x4 ar[2];
        #pragma unroll
        for (int s = 0; s < 2; ++s) {
            ar[s] = __builtin_amdgcn_mfma_f32_16x16x32_bf16(Ar2[0], Bh[s][0].v, arinit, 0,0,0);
            ar[s] = __builtin_amdgcn_mfma_f32_16x16x32_bf16(Ar2[1], Bh[s][1].v, ar[s], 0,0,0);
            ar[s] = __builtin_amdgcn_mfma_f32_16x16x32_bf16(Ar2f,   Bf[s].v,    ar[s], 0,0,0);
        }

        #pragma unroll
        for (int s = 0; s < 2; ++s) {
            const float rr    = sigmoid_fast(ar[s][0]);
            const float gg    = sigmoid_fast(ar[s][1]);
            const float bb    = sigmoid_fast(ar[s][2]);
            const float sigma = softplus_fast(ar[s][3]);
            const float tau   = sigma * cur[s][6];
            if (g == 0) out[pair * 32 + s * 16 + sl] = make_float4(tau, rr, gg, bb);
        }

        #pragma unroll
        for (int s = 0; s < 2; ++s)
            #pragma unroll
            for (int i = 0; i < 7; ++i) cur[s][i] = nxt[s][i];
    }
}

// ---------------------------------------------------------------------------
// Kernel 2: one wave per ray — scan tau, gate, reduce.
// ---------------------------------------------------------------------------
__global__ __launch_bounds__(256) void nerf_render_kernel(
    const float4* __restrict__ smp,
    const int*    __restrict__ packing,
    const float*  __restrict__ bg,
    float*        __restrict__ out)
{
    const int gtid = blockIdx.x * blockDim.x + threadIdx.x;
    const int ray  = gtid >> 6;
    const int lane = threadIdx.x & 63;
    if (ray >= N_RAYS) return;

    const int start = packing[2 * ray];
    const int count = packing[2 * ray + 1];

    float tau = 0.0f, r = 0.0f, g = 0.0f, b = 0.0f;
    if (lane < count) {
        const float4 v = smp[start + lane];
        tau = v.x; r = v.y; g = v.z; b = v.w;
    }

    float incl = tau;
    #pragma unroll
    for (int off = 1; off < 64; off <<= 1) {
        const float v = __shfl_up(incl, off, 64);
        if (lane >= off) incl += v;
    }
    const float c_excl = incl - tau;

    const float T     = __expf(-c_excl);
    const float alpha = 1.0f - __expf(-tau);
    float w = (lane < count && T > THRESH) ? T * alpha : 0.0f;

    float cr = r * w, cg = g * w, cb = b * w;

    #pragma unroll
    for (int off = 32; off > 0; off >>= 1) {
        cr += __shfl_down(cr, off, 64);
        cg += __shfl_down(cg, off, 64);
        cb += __shfl_down(cb, off, 64);
        w  += __shfl_down(w,  off, 64);
    }

    if (lane == 0) {
        out[ray * 3 + 0] = cr + bg[0] * (1.0f - w);
        out[ray * 3 + 1] = cg + bg[1] * (1.0f - w);
        out[ray * 3 + 2] = cb + bg[2] * (1.0f - w);
    }
}

extern "C" void kernel_launch(void* const* d_in, const int* in_sizes, int n_in,
                              void* d_out, int out_size, void* d_ws, size_t ws_size,
                              hipStream_t stream) {
    const float* samples  = (const float*)d_in[0];
    const int*   packing  = (const int*)  d_in[1];
    const float* w1       = (const float*)d_in[3];
    const float* b1       = (const float*)d_in[4];
    const float* w2       = (const float*)d_in[5];
    const float* b2       = (const float*)d_in[6];
    const float* w_sigma  = (const float*)d_in[7];
    const float* b_sigma  = (const float*)d_in[8];
    const float* w_rgb1   = (const float*)d_in[9];
    const float* b_rgb1   = (const float*)d_in[10];
    const float* w_rgb2   = (const float*)d_in[11];
    const float* b_rgb2   = (const float*)d_in[12];
    const float* bg       = (const float*)d_in[13];

    float4* smp = (float4*)d_ws;     // N_SAMPLES * 16 B = 16 MiB
    float*  out = (float*)d_out;

    // 2048 blocks x 4 waves = 8192 waves; 8 pairs (16 tiles) per wave.
    nerf_mlp_mfma<<<2048, 256, 0, stream>>>(
        samples, w1, b1, w2, b2, w_sigma, b_sigma,
        w_rgb1, b_rgb1, w_rgb2, b_rgb2, smp);

    nerf_render_kernel<<<(N_RAYS * 64) / 256, 256, 0, stream>>>(smp, packing, bg, out);
}

// Round 7
// 53.621 us; speedup vs baseline: 2.7302x; 1.0235x over previous
//
#include <hip/hip_runtime.h>
#include <hip/hip_bf16.h>
#include <math.h>
#include <stdint.h>

#define N_RAYS    32768
#define N_SAMPLES (N_RAYS * 32)
#define THRESH 0.0001f

typedef __attribute__((ext_vector_type(8))) __bf16 bf16x8;
typedef __attribute__((ext_vector_type(4))) float  f32x4;
typedef float f4a __attribute__((ext_vector_type(4), aligned(4)));  // 4B-aligned float4

union FragU { __hip_bfloat162 h2[4]; uint32_t w[4]; bf16x8 v; };

// compiler-modeled packed f32->bf16 (hazard-safe v_cvt_pk_bf16_f32)
__device__ inline __hip_bfloat162 pk2(float lo, float hi) {
    float2 t; t.x = lo; t.y = hi;
    return __float22bfloat162_rn(t);
}

__device__ inline bf16x8 pack8(const float* vals) {
    FragU u;
    u.h2[0] = pk2(vals[0], vals[1]);
    u.h2[1] = pk2(vals[2], vals[3]);
    u.h2[2] = pk2(vals[4], vals[5]);
    u.h2[3] = pk2(vals[6], vals[7]);
    return u.v;
}

__device__ inline float rcp_fast(float x) {
    float r;
    asm("v_rcp_f32 %0, %1" : "=v"(r) : "v"(x));
    return r;
}
__device__ inline float sigmoid_fast(float x) { return rcp_fast(1.0f + __expf(-x)); }
__device__ inline float softplus_fast(float x) {
    const float e = __expf(-fabsf(x));
    return fmaxf(x, 0.0f) + __logf(1.0f + e);
}

// ---------------------------------------------------------------------------
// Pure-register MFMA MLP. One wave = 128 contiguous samples (4 pairs of
// 16-sample tiles, fully unrolled, dual-stream per pair).
// Sample on lane&15 = N axis. D layout: n=lane&15, m=4*(lane>>4)+reg.
// B k-mapping of each layer == previous layer's D register layout:
//   slot (g, q) <-> j = 16*(2c + (q>>2)) + 4*g + (q&3)
// => B_next = cvt_pk(relu(acc_prev)) in-lane: no LDS, no cross-lane moves.
// All 64 lanes load their sample row (g-groups duplicate; unused B k-slots
// may hold garbage because the matching A k-slots are zero).
// Biases enter through the MFMA C-operand. sigma rides rgb2 as row m=3.
// ---------------------------------------------------------------------------
__global__ __launch_bounds__(256, 2) void nerf_mlp_mfma(
    const float* __restrict__ samples,   // (N_SAMPLES, 7)
    const float* __restrict__ w1,        // (3, 64)
    const float* __restrict__ b1,        // (64)
    const float* __restrict__ w2,        // (64, 32)
    const float* __restrict__ b2,        // (32)
    const float* __restrict__ w_sigma,   // (32, 1)
    const float* __restrict__ b_sigma,   // (1)
    const float* __restrict__ w_rgb1,    // (35, 64)
    const float* __restrict__ b_rgb1,    // (64)
    const float* __restrict__ w_rgb2,    // (64, 3)
    const float* __restrict__ b_rgb2,    // (3)
    float4* __restrict__ out)            // (N_SAMPLES): tau, r, g, b
{
    const int lane = threadIdx.x & 63;
    const int g    = lane >> 4;
    const int sl   = lane & 15;
    const int wgid = (blockIdx.x * blockDim.x + threadIdx.x) >> 6;  // 0..8191
    const int base0 = wgid * 128;      // this wave's 128-sample chunk

    // ---- staged sample loads: sa = s[0..3], sb = s[3..6] (overlap at s[3])
    f4a sa[4][2], sb[4][2];
    {   // issue pair 0 ASAP
        const float* sp0 = samples + (size_t)(base0 + sl) * 7;
        const float* sp1 = samples + (size_t)(base0 + 16 + sl) * 7;
        sa[0][0] = *(const f4a*)sp0;  sb[0][0] = *(const f4a*)(sp0 + 3);
        sa[0][1] = *(const f4a*)sp1;  sb[0][1] = *(const f4a*)(sp1 + 3);
    }

    // ---------------- weight fragments (permuted k-indexing) ----------------
    bf16x8 A1[4], A2[2][2], Ar1a[4], Ar1b[4], Ar2[2], Ar2f;

    #pragma unroll
    for (int t = 0; t < 4; ++t) {        // A1 = [w1;b1]^T; B1 k-slots: g==0, q=0..3
        float v[8] = {0,0,0,0,0,0,0,0};
        if (g == 0) {
            const int j = t*16 + sl;
            v[0] = w1[j]; v[1] = w1[64+j]; v[2] = w1[128+j]; v[3] = b1[j];
        }
        A1[t] = pack8(v);
    }
    #pragma unroll
    for (int t = 0; t < 2; ++t)          // A2 = w2^T; k-slot q <-> h1 index j(c,g,q)
        #pragma unroll
        for (int c = 0; c < 2; ++c) {
            float v[8];
            #pragma unroll
            for (int q = 0; q < 8; ++q) {
                const int j = 16*(2*c + (q>>2)) + 4*g + (q&3);
                v[q] = w2[j*32 + t*16 + sl];
            }
            A2[t][c] = pack8(v);
        }
    #pragma unroll
    for (int t = 0; t < 4; ++t) {        // Ar1a = w_rgb1^T (feats); f(g,q)
        float v[8];
        #pragma unroll
        for (int q = 0; q < 8; ++q) {
            const int f = 16*(q>>2) + 4*g + (q&3);
            v[q] = w_rgb1[f*64 + t*16 + sl];
        }
        Ar1a[t] = pack8(v);
    }
    #pragma unroll
    for (int t = 0; t < 4; ++t) {        // Ar1b = dirs rows + b_rgb1 aug (g==0 slots)
        float v[8] = {0,0,0,0,0,0,0,0};
        if (g == 0) {
            const int j = t*16 + sl;
            v[0] = w_rgb1[32*64 + j]; v[1] = w_rgb1[33*64 + j];
            v[2] = w_rgb1[34*64 + j]; v[3] = b_rgb1[j];
        }
        Ar1b[t] = pack8(v);
    }
    #pragma unroll
    for (int c = 0; c < 2; ++c) {        // Ar2 = w_rgb2^T rows m=0..2; k <-> hh(c,g,q)
        float v[8];
        #pragma unroll
        for (int q = 0; q < 8; ++q) {
            const int hh = 16*(2*c + (q>>2)) + 4*g + (q&3);
            v[q] = (sl < 3) ? w_rgb2[hh*3 + sl] : 0.0f;
        }
        Ar2[c] = pack8(v);
    }
    {                                    // Ar2f = w_sigma on row m=3, feats kstep
        float v[8];
        #pragma unroll
        for (int q = 0; q < 8; ++q) {
            const int f = 16*(q>>2) + 4*g + (q&3);
            v[q] = (sl == 3) ? w_sigma[f] : 0.0f;
        }
        Ar2f = pack8(v);
    }
    // bias C-inits (C layout == D layout: m = 4g + r)
    f32x4 b2i[2];
    #pragma unroll
    for (int t = 0; t < 2; ++t)
        #pragma unroll
        for (int r = 0; r < 4; ++r)
            b2i[t][r] = b2[16*t + 4*g + r];
    f32x4 arinit;
    arinit[0] = b_rgb2[0]; arinit[1] = b_rgb2[1];
    arinit[2] = b_rgb2[2]; arinit[3] = b_sigma[0];

    const float biasone = (g == 0) ? 1.0f : 0.0f;   // hoisted bias-slot constant
    const f32x4 zero4 = {0.f, 0.f, 0.f, 0.f};

    #pragma unroll
    for (int it = 0; it < 4; ++it) {
        // ---- prefetch next pair (static rotating buffers, no copies)
        if (it < 3) {
            const int nb = base0 + (it + 1) * 32;
            const float* sp0 = samples + (size_t)(nb + sl) * 7;
            const float* sp1 = samples + (size_t)(nb + 16 + sl) * 7;
            sa[it+1][0] = *(const f4a*)sp0;  sb[it+1][0] = *(const f4a*)(sp0 + 3);
            sa[it+1][1] = *(const f4a*)sp1;  sb[it+1][1] = *(const f4a*)(sp1 + 3);
        }

        // ---- input fragments for both streams
        FragU b1u[2], bd[2];
        #pragma unroll
        for (int s = 0; s < 2; ++s) {
            b1u[s].h2[0] = pk2(sa[it][s].x, sa[it][s].y);
            b1u[s].h2[1] = pk2(sa[it][s].z, biasone);
            b1u[s].w[2] = 0; b1u[s].w[3] = 0;
            bd[s].h2[0]  = pk2(sb[it][s].x, sb[it][s].y);
            bd[s].h2[1]  = pk2(sb[it][s].z, biasone);
            bd[s].w[2] = 0; bd[s].w[3] = 0;
        }

        // -------- layer1: h1 = relu(w1aug^T . posaug), 2 streams --------
        f32x4 accL1[2][4];
        #pragma unroll
        for (int t = 0; t < 4; ++t)
            #pragma unroll
            for (int s = 0; s < 2; ++s)
                accL1[s][t] = __builtin_amdgcn_mfma_f32_16x16x32_bf16(A1[t], b1u[s].v, zero4, 0,0,0);

        FragU B2c[2][2];
        #pragma unroll
        for (int s = 0; s < 2; ++s)
            #pragma unroll
            for (int c = 0; c < 2; ++c) {
                B2c[s][c].h2[0] = pk2(fmaxf(accL1[s][2*c  ][0],0.f), fmaxf(accL1[s][2*c  ][1],0.f));
                B2c[s][c].h2[1] = pk2(fmaxf(accL1[s][2*c  ][2],0.f), fmaxf(accL1[s][2*c  ][3],0.f));
                B2c[s][c].h2[2] = pk2(fmaxf(accL1[s][2*c+1][0],0.f), fmaxf(accL1[s][2*c+1][1],0.f));
                B2c[s][c].h2[3] = pk2(fmaxf(accL1[s][2*c+1][2],0.f), fmaxf(accL1[s][2*c+1][3],0.f));
            }

        // -------- layer2: feats = w2^T . h1 (+b2 via C-init) --------
        f32x4 accL2[2][2];
        #pragma unroll
        for (int t = 0; t < 2; ++t)
            #pragma unroll
            for (int s = 0; s < 2; ++s) {
                accL2[s][t] = __builtin_amdgcn_mfma_f32_16x16x32_bf16(A2[t][0], B2c[s][0].v, b2i[t], 0,0,0);
                accL2[s][t] = __builtin_amdgcn_mfma_f32_16x16x32_bf16(A2[t][1], B2c[s][1].v, accL2[s][t], 0,0,0);
            }
        FragU Bf[2];
        #pragma unroll
        for (int s = 0; s < 2; ++s) {
            Bf[s].h2[0] = pk2(accL2[s][0][0], accL2[s][0][1]);
            Bf[s].h2[1] = pk2(accL2[s][0][2], accL2[s][0][3]);
            Bf[s].h2[2] = pk2(accL2[s][1][0], accL2[s][1][1]);
            Bf[s].h2[3] = pk2(accL2[s][1][2], accL2[s][1][3]);
        }

        // -------- rgb1: h = relu(w_rgb1^T . [feats; dirs; 1]) --------
        f32x4 ah[2][4];
        #pragma unroll
        for (int t = 0; t < 4; ++t)
            #pragma unroll
            for (int s = 0; s < 2; ++s) {
                ah[s][t] = __builtin_amdgcn_mfma_f32_16x16x32_bf16(Ar1a[t], Bf[s].v, zero4, 0,0,0);
                ah[s][t] = __builtin_amdgcn_mfma_f32_16x16x32_bf16(Ar1b[t], bd[s].v, ah[s][t], 0,0,0);
            }
        FragU Bh[2][2];
        #pragma unroll
        for (int s = 0; s < 2; ++s)
            #pragma unroll
            for (int c = 0; c < 2; ++c) {
                Bh[s][c].h2[0] = pk2(fmaxf(ah[s][2*c  ][0],0.f), fmaxf(ah[s][2*c  ][1],0.f));
                Bh[s][c].h2[1] = pk2(fmaxf(ah[s][2*c  ][2],0.f), fmaxf(ah[s][2*c  ][3],0.f));
                Bh[s][c].h2[2] = pk2(fmaxf(ah[s][2*c+1][0],0.f), fmaxf(ah[s][2*c+1][1],0.f));
                Bh[s][c].h2[3] = pk2(fmaxf(ah[s][2*c+1][2],0.f), fmaxf(ah[s][2*c+1][3],0.f));
            }

        // -------- rgb2 (+sigma row m=3), biases via C-init --------
        f32x4 ar[2];
        #pragma unroll
        for (int s = 0; s < 2; ++s) {
            ar[s] = __builtin_amdgcn_mfma_f32_16x16x32_bf16(Ar2[0], Bh[s][0].v, arinit, 0,0,0);
            ar[s] = __builtin_amdgcn_mfma_f32_16x16x32_bf16(Ar2[1], Bh[s][1].v, ar[s], 0,0,0);
            ar[s] = __builtin_amdgcn_mfma_f32_16x16x32_bf16(Ar2f,   Bf[s].v,    ar[s], 0,0,0);
        }

        #pragma unroll
        for (int s = 0; s < 2; ++s) {
            const float rr    = sigmoid_fast(ar[s][0]);
            const float gg    = sigmoid_fast(ar[s][1]);
            const float bb    = sigmoid_fast(ar[s][2]);
            const float sigma = softplus_fast(ar[s][3]);
            const float tau   = sigma * sb[it][s].w;      // dt = s[6]
            if (g == 0) out[base0 + it * 32 + s * 16 + sl] = make_float4(tau, rr, gg, bb);
        }
    }
}

// ---------------------------------------------------------------------------
// Kernel 2: one wave per ray — scan tau, gate, reduce.
// ---------------------------------------------------------------------------
__global__ __launch_bounds__(256) void nerf_render_kernel(
    const float4* __restrict__ smp,
    const int*    __restrict__ packing,
    const float*  __restrict__ bg,
    float*        __restrict__ out)
{
    const int gtid = blockIdx.x * blockDim.x + threadIdx.x;
    const int ray  = gtid >> 6;
    const int lane = threadIdx.x & 63;
    if (ray >= N_RAYS) return;

    const int start = packing[2 * ray];
    const int count = packing[2 * ray + 1];

    float tau = 0.0f, r = 0.0f, g = 0.0f, b = 0.0f;
    if (lane < count) {
        const float4 v = smp[start + lane];
        tau = v.x; r = v.y; g = v.z; b = v.w;
    }

    float incl = tau;
    #pragma unroll
    for (int off = 1; off < 64; off <<= 1) {
        const float v = __shfl_up(incl, off, 64);
        if (lane >= off) incl += v;
    }
    const float c_excl = incl - tau;

    const float T     = __expf(-c_excl);
    const float alpha = 1.0f - __expf(-tau);
    float w = (lane < count && T > THRESH) ? T * alpha : 0.0f;

    float cr = r * w, cg = g * w, cb = b * w;

    #pragma unroll
    for (int off = 32; off > 0; off >>= 1) {
        cr += __shfl_down(cr, off, 64);
        cg += __shfl_down(cg, off, 64);
        cb += __shfl_down(cb, off, 64);
        w  += __shfl_down(w,  off, 64);
    }

    if (lane == 0) {
        out[ray * 3 + 0] = cr + bg[0] * (1.0f - w);
        out[ray * 3 + 1] = cg + bg[1] * (1.0f - w);
        out[ray * 3 + 2] = cb + bg[2] * (1.0f - w);
    }
}

extern "C" void kernel_launch(void* const* d_in, const int* in_sizes, int n_in,
                              void* d_out, int out_size, void* d_ws, size_t ws_size,
                              hipStream_t stream) {
    const float* samples  = (const float*)d_in[0];
    const int*   packing  = (const int*)  d_in[1];
    const float* w1       = (const float*)d_in[3];
    const float* b1       = (const float*)d_in[4];
    const float* w2       = (const float*)d_in[5];
    const float* b2       = (const float*)d_in[6];
    const float* w_sigma  = (const float*)d_in[7];
    const float* b_sigma  = (const float*)d_in[8];
    const float* w_rgb1   = (const float*)d_in[9];
    const float* b_rgb1   = (const float*)d_in[10];
    const float* w_rgb2   = (const float*)d_in[11];
    const float* b_rgb2   = (const float*)d_in[12];
    const float* bg       = (const float*)d_in[13];

    float4* smp = (float4*)d_ws;     // N_SAMPLES * 16 B = 16 MiB
    float*  out = (float*)d_out;

    // 2048 blocks x 4 waves = 8192 waves x 128 contiguous samples each.
    nerf_mlp_mfma<<<2048, 256, 0, stream>>>(
        samples, w1, b1, w2, b2, w_sigma, b_sigma,
        w_rgb1, b_rgb1, w_rgb2, b_rgb2, smp);

    nerf_render_kernel<<<(N_RAYS * 64) / 256, 256, 0, stream>>>(smp, packing, bg, out);
}